// Round 6
// baseline (323.086 us; speedup 1.0000x reference)
//
#include <hip/hip_runtime.h>

#define N_NODES 50000
#define N_EDGES 800000
#define IN_CH 128
#define HID_CH 256
#define OUT_CH 128

constexpr int EPB_F = 400;                       // edges per fill chunk
constexpr int FILL_BLOCKS = N_EDGES / EPB_F;     // 2000 (exact), g = b & 7 (250/g)
constexpr int TOTG = 8 * N_NODES;                // g-major count array size
constexpr int SCAN_BLK = 1024;
constexpr int NBG = (TOTG + SCAN_BLK - 1) / SCAN_BLK;  // 391

typedef __attribute__((ext_vector_type(8))) short bf16x8;
typedef __attribute__((ext_vector_type(4))) float f32x4;
typedef __attribute__((ext_vector_type(4))) unsigned int u32x4;

// ---------------- bf16 helpers ----------------

__device__ __forceinline__ unsigned int bf16rn(float x) {
    unsigned int u = __float_as_uint(x);
    return (u + 0x7fffu + ((u >> 16) & 1u)) >> 16;   // round-to-nearest-even
}

__device__ __forceinline__ void split2(float x0, float x1,
                                       unsigned int& h, unsigned int& l) {
    unsigned int h0 = bf16rn(x0), h1 = bf16rn(x1);
    float f0 = __uint_as_float(h0 << 16), f1 = __uint_as_float(h1 << 16);
    unsigned int l0 = bf16rn(x0 - f0), l1 = bf16rn(x1 - f1);
    h = h0 | (h1 << 16);
    l = l0 | (l1 << 16);
}

__device__ __forceinline__ bf16x8 asbf(u32x4 v) {
    return __builtin_bit_cast(bf16x8, v);
}

// ---------------- fp32 -> bf16 row copy ----------------

__global__ void k_tobf(const float* __restrict__ x, unsigned short* __restrict__ xb,
                       int n8) {
    int i = blockIdx.x * blockDim.x + threadIdx.x;
    if (i >= n8) return;
    const float4* p = (const float4*)(x + (size_t)i * 8);
    float4 a = p[0], b = p[1];
    u32x4 w;
    w.x = bf16rn(a.x) | (bf16rn(a.y) << 16);
    w.y = bf16rn(a.z) | (bf16rn(a.w) << 16);
    w.z = bf16rn(b.x) | (bf16rn(b.y) << 16);
    w.w = bf16rn(b.z) | (bf16rn(b.w) << 16);
    *(u32x4*)(xb + (size_t)i * 8) = w;
}

// ------------- CSR construction: g-MAJOR planes, self-loops excluded -------------
// col[800K] = 8 contiguous planes; plane g holds edges of fill-chunks with c%8==g,
// grouped by dst inside the plane. All writers of plane g are blocks b%8==g (one
// XCD under round-robin) -> single-L2 line ownership for the scatter.
// Edge e -> chunk c = e/EPB_F -> g = c&7. offG[g*N+v] from scan of cntG (g-major).

__global__ void k_initG(int* __restrict__ cntG, int* __restrict__ curG) {
    int i = blockIdx.x * blockDim.x + threadIdx.x;
    if (i < TOTG) { cntG[i] = 0; curG[i] = 0; }
}

__global__ void k_histG(const int* __restrict__ dst, int* __restrict__ cntG) {
    int e = blockIdx.x * blockDim.x + threadIdx.x;
    if (e < N_EDGES) {
        int g = (e / EPB_F) & 7;
        atomicAdd(&cntG[g * N_NODES + dst[e]], 1);
    }
}

__global__ void k_scan1(const int* __restrict__ cnt, int* __restrict__ incl,
                        int* __restrict__ part, int n) {
    __shared__ int s[SCAN_BLK];
    int t = threadIdx.x;
    int i = blockIdx.x * SCAN_BLK + t;
    int v = (i < n) ? cnt[i] : 0;
    s[t] = v; __syncthreads();
    for (int o = 1; o < SCAN_BLK; o <<= 1) {
        int a = (t >= o) ? s[t - o] : 0;
        __syncthreads();
        s[t] += a;
        __syncthreads();
    }
    if (i < n) incl[i] = s[t];
    if (t == SCAN_BLK - 1) part[blockIdx.x] = s[t];
}

__global__ void k_scan2(int* __restrict__ part, int n) {   // n <= SCAN_BLK partials
    __shared__ int s[SCAN_BLK];
    int t = threadIdx.x;
    int v = (t < n) ? part[t] : 0;
    s[t] = v; __syncthreads();
    for (int o = 1; o < SCAN_BLK; o <<= 1) {
        int a = (t >= o) ? s[t - o] : 0;
        __syncthreads();
        s[t] += a;
        __syncthreads();
    }
    if (t < n) part[t] = s[t] - v;    // exclusive
}

// offG[i] = exclusive scan (in place over incl); offG[TOTG] = N_EDGES sentinel
__global__ void k_offG(int* __restrict__ incl, const int* __restrict__ cntG,
                       const int* __restrict__ part) {
    int i = blockIdx.x * blockDim.x + threadIdx.x;
    if (i < TOTG)       incl[i] = part[i >> 10] + incl[i] - cntG[i];
    else if (i == TOTG) incl[i] = N_EDGES;
}

// dis[v] = rsqrt(1 + in-degree)  (cntG still intact after scan)
__global__ void k_post(const int* __restrict__ cntG, float* __restrict__ dis) {
    int v = blockIdx.x * blockDim.x + threadIdx.x;
    if (v < N_NODES) {
        int d = 1;
        #pragma unroll
        for (int g = 0; g < 8; ++g) d += cntG[g * N_NODES + v];
        dis[v] = rsqrtf((float)d);
    }
}

__global__ __launch_bounds__(128)
void k_fillG(const int* __restrict__ src, const int* __restrict__ dst,
             const int* __restrict__ offG, int* __restrict__ curG,
             int* __restrict__ col) {
    int b = blockIdx.x;                 // chunk id == block id (2000 blocks)
    int g = b & 7;
    int e0 = b * EPB_F;
    for (int i = threadIdx.x; i < EPB_F; i += 128) {
        int e = e0 + i;
        int d = dst[e];
        int slot = g * N_NODES + d;
        int pos = offG[slot] + atomicAdd(&curG[slot], 1);
        col[pos] = src[e];
    }
}

// ---- bf16 aggregation over 8 g-segments + implicit self loop  (F = 128) --------
// 4 waves/block, one node per wave. Lanes 0-31 take edge j, lanes 32-63 edge j+1;
// each lane covers 4 channels (8 B load). Cross-half reduce via shfl_xor(32).
// Segment bounds are wave-uniform scalar loads (all 16 hoisted by the compiler).

template<bool BIAS, bool RELU>
__global__ __launch_bounds__(256)
void k_agg8(const unsigned short* __restrict__ featb, const int* __restrict__ col,
            const int* __restrict__ offG, const float* __restrict__ dis,
            const float* __restrict__ bias, float* __restrict__ out) {
    int wid  = threadIdx.x >> 6;
    int lane = threadIdx.x & 63;
    int v = blockIdx.x * 4 + wid;          // grid is exactly N_NODES/4
    float disv = dis[v];
    int half = lane >> 5;                  // which edge of the pair
    int q    = lane & 31;                  // channel quad: ch q*4..q*4+3
    float4 acc = make_float4(0.f, 0.f, 0.f, 0.f);
    #pragma unroll
    for (int g = 0; g < 8; ++g) {
        int s = offG[g * N_NODES + v];
        int e = offG[g * N_NODES + v + 1];
        for (int base = s; base < e; base += 64) {
            int n = min(64, e - base);
            int   cv = 0;
            float wv = 0.f;
            if (lane < n) {
                cv = col[base + lane];
                wv = dis[cv] * disv;
            }
            auto pair = [&](int j) {
                int   c = __shfl(cv, j + half);   // j+half==n on odd tail -> w=0
                float w = __shfl(wv, j + half);
                uint2 d = *(const uint2*)&featb[(size_t)c * 128 + q * 4];
                acc.x = fmaf(w, __uint_as_float(d.x << 16),         acc.x);
                acc.y = fmaf(w, __uint_as_float(d.x & 0xffff0000u), acc.y);
                acc.z = fmaf(w, __uint_as_float(d.y << 16),         acc.z);
                acc.w = fmaf(w, __uint_as_float(d.y & 0xffff0000u), acc.w);
            };
            int j = 0;
            for (; j + 8 <= n; j += 8) { pair(j); pair(j + 2); pair(j + 4); pair(j + 6); }
            for (; j < n; j += 2) pair(j);
        }
    }
    acc.x += __shfl_xor(acc.x, 32);
    acc.y += __shfl_xor(acc.y, 32);
    acc.z += __shfl_xor(acc.z, 32);
    acc.w += __shfl_xor(acc.w, 32);
    if (half == 0) {
        // self loop: w = dis[v]^2, row v (coalesced)
        float ws = disv * disv;
        uint2 dv = *(const uint2*)&featb[(size_t)v * 128 + q * 4];
        float4 o;
        o.x = fmaf(ws, __uint_as_float(dv.x << 16),         acc.x);
        o.y = fmaf(ws, __uint_as_float(dv.x & 0xffff0000u), acc.y);
        o.z = fmaf(ws, __uint_as_float(dv.y << 16),         acc.z);
        o.w = fmaf(ws, __uint_as_float(dv.y & 0xffff0000u), acc.w);
        if (BIAS) {
            float4 b = *(const float4*)&bias[q * 4];
            o.x += b.x; o.y += b.y; o.z += b.z; o.w += b.w;
        }
        if (RELU) {
            o.x = fmaxf(o.x, 0.f); o.y = fmaxf(o.y, 0.f);
            o.z = fmaxf(o.z, 0.f); o.w = fmaxf(o.w, 0.f);
        }
        *(float4*)&out[(size_t)v * 128 + q * 4] = o;
    }
}

// ---- W split into MFMA-fragment-ordered bf16 hi/lo --------------------------
// Fragment layout (16x16x32 bf16): B col n = lane&15, k = (lane>>4)*8 + i.

template<int K, int NC>
__global__ void k_wsplit(const float* __restrict__ W, u32x4* __restrict__ Wf) {
    constexpr int KT = K / 32, NT = NC / 16;
    int tid = blockIdx.x * blockDim.x + threadIdx.x;
    if (tid >= KT * NT * 64) return;
    int lane = tid & 63;
    int ntk  = tid >> 6;           // kt*NT + nt
    int kt = ntk / NT, nt = ntk % NT;
    int kb = kt * 32 + (lane >> 4) * 8;
    int n  = nt * 16 + (lane & 15);
    unsigned int hh[4], ll[4];
    #pragma unroll
    for (int j = 0; j < 4; ++j) {
        float x0 = W[(size_t)(kb + 2 * j) * NC + n];
        float x1 = W[(size_t)(kb + 2 * j + 1) * NC + n];
        split2(x0, x1, hh[j], ll[j]);
    }
    Wf[(size_t)(ntk * 2 + 0) * 64 + lane] = (u32x4){hh[0], hh[1], hh[2], hh[3]};
    Wf[(size_t)(ntk * 2 + 1) * 64 + lane] = (u32x4){ll[0], ll[1], ll[2], ll[3]};
}

// ---- MFMA GEMM: out[M,NC] = A[M,K] @ W[K,NC] (+bias, relu), split-bf16 3-pass ----

template<int K, int NC, bool BIAS, bool RELU, bool BF16OUT>
__global__ __launch_bounds__(128)
void k_gemm_mfma(const float* __restrict__ A, const u32x4* __restrict__ Wf,
                 const float* __restrict__ bias, void* __restrict__ outv, int M) {
    constexpr int KT = K / 32, NT = NC / 16, NTW = NT / 2;
    int lane = threadIdx.x & 63;
    int wid  = threadIdx.x >> 6;
    int lq = lane >> 4;            // 0..3
    int lr = lane & 15;
    int kq = lq * 8;
    int rbase = blockIdx.x * 32;
    int nt0 = wid * NTW;

    f32x4 acc[2][NTW];
    #pragma unroll
    for (int s = 0; s < 2; ++s)
        #pragma unroll
        for (int t = 0; t < NTW; ++t)
            acc[s][t] = (f32x4){0.f, 0.f, 0.f, 0.f};

    for (int kt = 0; kt < KT; ++kt) {
        bf16x8 ah[2], al[2];
        #pragma unroll
        for (int s = 0; s < 2; ++s) {
            int row = rbase + s * 16 + lr;
            const float* Ar = A + (size_t)min(row, M - 1) * K + kt * 32 + kq;
            float4 u = *(const float4*)Ar;
            float4 v = *(const float4*)(Ar + 4);
            unsigned int h0, l0, h1, l1, h2, l2, h3, l3;
            split2(u.x, u.y, h0, l0); split2(u.z, u.w, h1, l1);
            split2(v.x, v.y, h2, l2); split2(v.z, v.w, h3, l3);
            ah[s] = asbf((u32x4){h0, h1, h2, h3});
            al[s] = asbf((u32x4){l0, l1, l2, l3});
        }
        #pragma unroll
        for (int t = 0; t < NTW; ++t) {
            int nt = nt0 + t;
            const u32x4* wp = Wf + (size_t)((kt * NT + nt) * 2) * 64 + lane;
            bf16x8 bh = asbf(wp[0]);
            bf16x8 bl = asbf(wp[64]);
            // D = Ah*Wh + Al*Wh + Ah*Wl  (drop Al*Wl ~ 2^-18)
            acc[0][t] = __builtin_amdgcn_mfma_f32_16x16x32_bf16(ah[0], bh, acc[0][t], 0, 0, 0);
            acc[1][t] = __builtin_amdgcn_mfma_f32_16x16x32_bf16(ah[1], bh, acc[1][t], 0, 0, 0);
            acc[0][t] = __builtin_amdgcn_mfma_f32_16x16x32_bf16(al[0], bh, acc[0][t], 0, 0, 0);
            acc[1][t] = __builtin_amdgcn_mfma_f32_16x16x32_bf16(al[1], bh, acc[1][t], 0, 0, 0);
            acc[0][t] = __builtin_amdgcn_mfma_f32_16x16x32_bf16(ah[0], bl, acc[0][t], 0, 0, 0);
            acc[1][t] = __builtin_amdgcn_mfma_f32_16x16x32_bf16(ah[1], bl, acc[1][t], 0, 0, 0);
        }
    }

    // epilogue: D col = lane&15, row = (lane>>4)*4 + j
    #pragma unroll
    for (int t = 0; t < NTW; ++t) {
        int colg = (nt0 + t) * 16 + lr;
        float bv = BIAS ? bias[colg] : 0.f;
        #pragma unroll
        for (int s = 0; s < 2; ++s) {
            #pragma unroll
            for (int j = 0; j < 4; ++j) {
                int row = rbase + s * 16 + lq * 4 + j;
                if (row < M) {
                    float o = acc[s][t][j] + bv;
                    if (RELU) o = fmaxf(o, 0.f);
                    if (BF16OUT)
                        ((unsigned short*)outv)[(size_t)row * NC + colg] = (unsigned short)bf16rn(o);
                    else
                        ((float*)outv)[(size_t)row * NC + colg] = o;
                }
            }
        }
    }
}

// ---------------- launch ----------------

extern "C" void kernel_launch(void* const* d_in, const int* in_sizes, int n_in,
                              void* d_out, int out_size, void* d_ws, size_t ws_size,
                              hipStream_t stream) {
    const float* x   = (const float*)d_in[0];
    const int*   ei  = (const int*)d_in[1];
    const int*   src = ei;
    const int*   dst = ei + N_EDGES;
    const float* W1  = (const float*)d_in[3];
    const float* b1  = (const float*)d_in[4];
    const float* W2  = (const float*)d_in[5];
    const float* b2  = (const float*)d_in[6];
    float* out = (float*)d_out;

    char* ws = (char*)d_ws;
    size_t o = 0;
    auto carve = [&](size_t bytes) {
        void* p = ws + o;
        o += (bytes + 255) & ~(size_t)255;
        return p;
    };
    int*   cntG   = (int*)  carve((size_t)TOTG * 4);
    int*   curG   = (int*)  carve((size_t)TOTG * 4);
    int*   inclG  = (int*)  carve((size_t)(TOTG + 1) * 4);  // becomes offG in place
    int*   partG  = (int*)  carve(SCAN_BLK * 4);
    float* dis    = (float*)carve(N_NODES * 4);
    int*   col    = (int*)  carve((size_t)N_EDGES * 4);
    float* agg1   = (float*)carve((size_t)N_NODES * 128 * 4);
    float* h1     = (float*)carve((size_t)N_NODES * 256 * 4);
    u32x4* Wf1    = (u32x4*)carve((size_t)(IN_CH/32) * (HID_CH/16) * 2 * 64 * 16);
    u32x4* Wf2    = (u32x4*)carve((size_t)(HID_CH/32) * (OUT_CH/16) * 2 * 64 * 16);
    int*   offG   = inclG;                 // in-place exclusive scan
    // Aliases (lifetimes by launch order):
    //   xb  aliases h1  : xb written first, dead after agg1; h1 written in gemm1
    //   t2b aliases agg1: agg1 dead after gemm1; t2b written by gemm2, read by agg2
    unsigned short* xb  = (unsigned short*)h1;
    unsigned short* t2b = (unsigned short*)agg1;

    const int B = 256;
    k_tobf  <<<(N_NODES * 128 / 8 + B - 1) / B, B, 0, stream>>>(x, xb, N_NODES * 128 / 8);
    k_initG <<<(TOTG + B - 1) / B, B, 0, stream>>>(cntG, curG);
    k_histG <<<(N_EDGES + B - 1) / B, B, 0, stream>>>(dst, cntG);
    k_scan1 <<<NBG, SCAN_BLK, 0, stream>>>(cntG, inclG, partG, TOTG);
    k_scan2 <<<1, SCAN_BLK, 0, stream>>>(partG, NBG);
    k_offG  <<<(TOTG + 1 + B - 1) / B, B, 0, stream>>>(inclG, cntG, partG);
    k_post  <<<(N_NODES + B - 1) / B, B, 0, stream>>>(cntG, dis);
    k_fillG <<<FILL_BLOCKS, 128, 0, stream>>>(src, dst, offG, curG, col);

    k_wsplit<IN_CH,  HID_CH><<<( (IN_CH/32)*(HID_CH/16)*64 + B - 1) / B, B, 0, stream>>>(W1, Wf1);
    k_wsplit<HID_CH, OUT_CH><<<( (HID_CH/32)*(OUT_CH/16)*64 + B - 1) / B, B, 0, stream>>>(W2, Wf2);

    // layer 1: agg1 = A xb ; h1 = relu(agg1 @ W1 + b1)   (clobbers xb, now dead)
    k_agg8<false, false><<<N_NODES / 4, 256, 0, stream>>>(xb, col, offG, dis, nullptr, agg1);
    k_gemm_mfma<IN_CH, HID_CH, true, true, false>
        <<<(N_NODES + 31) / 32, 128, 0, stream>>>(agg1, Wf1, b1, h1, N_NODES);

    // layer 2: t2b = bf16(h1 @ W2) ; out = relu(A t2b + b2)
    k_gemm_mfma<HID_CH, OUT_CH, false, false, true>
        <<<(N_NODES + 31) / 32, 128, 0, stream>>>(h1, Wf2, nullptr, t2b, N_NODES);
    k_agg8<true, true><<<N_NODES / 4, 256, 0, stream>>>(t2b, col, offG, dis, b2, out);
}

// Round 7
// 270.275 us; speedup vs baseline: 1.1954x; 1.1954x over previous
//
#include <hip/hip_runtime.h>

#define N_NODES 50000
#define N_EDGES 800000
#define IN_CH 128
#define HID_CH 256
#define OUT_CH 128

constexpr int TOTAL_E = N_EDGES + N_NODES;       // incl self loops (compacted col)
constexpr int EPB_F = 400;                       // edges per fill chunk
constexpr int FILL_BLOCKS = N_EDGES / EPB_F;     // 2000 (exact), g = b & 7
constexpr int TOTG = 8 * N_NODES;                // g-major count array size
constexpr int SCAN_BLK = 1024;
constexpr int NBG = (TOTG + SCAN_BLK - 1) / SCAN_BLK;     // 391
constexpr int NBN = (N_NODES + SCAN_BLK - 1) / SCAN_BLK;  // 49

typedef __attribute__((ext_vector_type(8))) short bf16x8;
typedef __attribute__((ext_vector_type(4))) float f32x4;
typedef __attribute__((ext_vector_type(4))) unsigned int u32x4;

// ---------------- bf16 helpers ----------------

__device__ __forceinline__ unsigned int bf16rn(float x) {
    unsigned int u = __float_as_uint(x);
    return (u + 0x7fffu + ((u >> 16) & 1u)) >> 16;   // round-to-nearest-even
}

__device__ __forceinline__ void split2(float x0, float x1,
                                       unsigned int& h, unsigned int& l) {
    unsigned int h0 = bf16rn(x0), h1 = bf16rn(x1);
    float f0 = __uint_as_float(h0 << 16), f1 = __uint_as_float(h1 << 16);
    unsigned int l0 = bf16rn(x0 - f0), l1 = bf16rn(x1 - f1);
    h = h0 | (h1 << 16);
    l = l0 | (l1 << 16);
}

__device__ __forceinline__ bf16x8 asbf(u32x4 v) {
    return __builtin_bit_cast(bf16x8, v);
}

// ---------------- fp32 -> bf16 row copy ----------------

__global__ void k_tobf(const float* __restrict__ x, unsigned short* __restrict__ xb,
                       int n8) {
    int i = blockIdx.x * blockDim.x + threadIdx.x;
    if (i >= n8) return;
    const float4* p = (const float4*)(x + (size_t)i * 8);
    float4 a = p[0], b = p[1];
    u32x4 w;
    w.x = bf16rn(a.x) | (bf16rn(a.y) << 16);
    w.y = bf16rn(a.z) | (bf16rn(a.w) << 16);
    w.z = bf16rn(b.x) | (bf16rn(b.y) << 16);
    w.w = bf16rn(b.z) | (bf16rn(b.w) << 16);
    *(u32x4*)(xb + (size_t)i * 8) = w;
}

// ------------- CSR construction -------------
// Producer side: 8 g-major planes (XCD-local scatter, b%8 -> one XCD's L2).
// Consumer side: k_compact folds planes into a flat per-node CSR (col, offN, len)
// with the self-loop appended (weight dis[v]^2 arises naturally from dis[c]*dis[v]).

__global__ void k_initG(int* __restrict__ cntG, int* __restrict__ curG) {
    int i = blockIdx.x * blockDim.x + threadIdx.x;
    if (i < TOTG) { cntG[i] = 0; curG[i] = 0; }
}

__global__ void k_histG(const int* __restrict__ dst, int* __restrict__ cntG) {
    int e = blockIdx.x * blockDim.x + threadIdx.x;
    if (e < N_EDGES) {
        int g = (e / EPB_F) & 7;
        atomicAdd(&cntG[g * N_NODES + dst[e]], 1);
    }
}

__global__ void k_scan1(const int* __restrict__ cnt, int* __restrict__ incl,
                        int* __restrict__ part, int n) {
    __shared__ int s[SCAN_BLK];
    int t = threadIdx.x;
    int i = blockIdx.x * SCAN_BLK + t;
    int v = (i < n) ? cnt[i] : 0;
    s[t] = v; __syncthreads();
    for (int o = 1; o < SCAN_BLK; o <<= 1) {
        int a = (t >= o) ? s[t - o] : 0;
        __syncthreads();
        s[t] += a;
        __syncthreads();
    }
    if (i < n) incl[i] = s[t];
    if (t == SCAN_BLK - 1) part[blockIdx.x] = s[t];
}

__global__ void k_scan2(int* __restrict__ part, int n) {   // n <= SCAN_BLK partials
    __shared__ int s[SCAN_BLK];
    int t = threadIdx.x;
    int v = (t < n) ? part[t] : 0;
    s[t] = v; __syncthreads();
    for (int o = 1; o < SCAN_BLK; o <<= 1) {
        int a = (t >= o) ? s[t - o] : 0;
        __syncthreads();
        s[t] += a;
        __syncthreads();
    }
    if (t < n) part[t] = s[t] - v;    // exclusive
}

// exclusive scan in place over incl; sentinel at [n] = total
__global__ void k_off(int* __restrict__ incl, const int* __restrict__ cnt,
                      const int* __restrict__ part, int n, int total) {
    int i = blockIdx.x * blockDim.x + threadIdx.x;
    if (i < n)       incl[i] = part[i >> 10] + incl[i] - cnt[i];
    else if (i == n) incl[i] = total;
}

// len[v] = 1 + in-degree (incl self loop); dis = rsqrt(len)
__global__ void k_deg(const int* __restrict__ cntG, int* __restrict__ len,
                      float* __restrict__ dis) {
    int v = blockIdx.x * blockDim.x + threadIdx.x;
    if (v < N_NODES) {
        int d = 1;
        #pragma unroll
        for (int g = 0; g < 8; ++g) d += cntG[g * N_NODES + v];
        len[v] = d;
        dis[v] = rsqrtf((float)d);
    }
}

__global__ __launch_bounds__(128)
void k_fillG(const int* __restrict__ src, const int* __restrict__ dst,
             const int* __restrict__ offG, int* __restrict__ curG,
             int* __restrict__ colG) {
    int b = blockIdx.x;                 // chunk id == block id (2000 blocks)
    int g = b & 7;
    int e0 = b * EPB_F;
    for (int i = threadIdx.x; i < EPB_F; i += 128) {
        int e = e0 + i;
        int d = dst[e];
        int slot = g * N_NODES + d;
        int pos = offG[slot] + atomicAdd(&curG[slot], 1);
        colG[pos] = src[e];
    }
}

// fold 8 plane-segments of node v into contiguous col[offN[v]..]; append self loop
__global__ __launch_bounds__(256)
void k_compact(const int* __restrict__ offG, const int* __restrict__ colG,
               const int* __restrict__ offN, int* __restrict__ col) {
    int wid  = threadIdx.x >> 6;
    int lane = threadIdx.x & 63;
    int v = blockIdx.x * 4 + wid;       // grid exactly N_NODES/4
    int pos = offN[v];
    #pragma unroll
    for (int g = 0; g < 8; ++g) {
        int s = offG[g * N_NODES + v];
        int e = offG[g * N_NODES + v + 1];   // g<7: next plane start; g=7,v=last: sentinel
        for (int i = lane; i < e - s; i += 64)
            col[pos + i] = colG[s + i];
        pos += e - s;
    }
    if (lane == 0) col[pos] = v;        // self loop at segment end
}

// ---- bf16 aggregation: out[v] = sum_{c in col[v]} dis[c]*dis[v] * featb[c] ----
// 4 waves/block, one node per wave. Lanes 0-31 edge j, lanes 32-63 edge j+1;
// each lane covers 4 channels (8 B load). Cross-half reduce via shfl_xor(32).
// Self loop is an ordinary entry (c==v -> w=dis[v]^2).

template<bool BIAS, bool RELU>
__global__ __launch_bounds__(256)
void k_agg_bf(const unsigned short* __restrict__ featb, const int* __restrict__ col,
              const int* __restrict__ offN, const int* __restrict__ len,
              const float* __restrict__ dis, const float* __restrict__ bias,
              float* __restrict__ out) {
    int wid  = threadIdx.x >> 6;
    int lane = threadIdx.x & 63;
    int v = blockIdx.x * 4 + wid;          // grid is exactly N_NODES/4
    int start = offN[v];
    int lenv  = len[v];
    float disv = dis[v];
    int half = lane >> 5;                  // which edge of the pair
    int q    = lane & 31;                  // channel quad: ch q*4..q*4+3
    float4 acc = make_float4(0.f, 0.f, 0.f, 0.f);
    for (int base = 0; base < lenv; base += 64) {
        int n = min(64, lenv - base);
        int   cv = 0;
        float wv = 0.f;
        if (lane < n) {
            cv = col[start + base + lane];
            wv = dis[cv] * disv;
        }
        auto pair = [&](int j) {
            int   c = __shfl(cv, j + half);   // j+half==n on odd tail -> w=0, c=0
            float w = __shfl(wv, j + half);
            uint2 d = *(const uint2*)&featb[(size_t)c * 128 + q * 4];
            acc.x = fmaf(w, __uint_as_float(d.x << 16),         acc.x);
            acc.y = fmaf(w, __uint_as_float(d.x & 0xffff0000u), acc.y);
            acc.z = fmaf(w, __uint_as_float(d.y << 16),         acc.z);
            acc.w = fmaf(w, __uint_as_float(d.y & 0xffff0000u), acc.w);
        };
        int j = 0;
        for (; j + 8 <= n; j += 8) { pair(j); pair(j + 2); pair(j + 4); pair(j + 6); }
        for (; j < n; j += 2) pair(j);
    }
    acc.x += __shfl_xor(acc.x, 32);
    acc.y += __shfl_xor(acc.y, 32);
    acc.z += __shfl_xor(acc.z, 32);
    acc.w += __shfl_xor(acc.w, 32);
    if (half == 0) {
        float4 o = acc;
        if (BIAS) {
            float4 b = *(const float4*)&bias[q * 4];
            o.x += b.x; o.y += b.y; o.z += b.z; o.w += b.w;
        }
        if (RELU) {
            o.x = fmaxf(o.x, 0.f); o.y = fmaxf(o.y, 0.f);
            o.z = fmaxf(o.z, 0.f); o.w = fmaxf(o.w, 0.f);
        }
        *(float4*)&out[(size_t)v * 128 + q * 4] = o;
    }
}

// ---- W split into MFMA-fragment-ordered bf16 hi/lo --------------------------
// Fragment layout (16x16x32 bf16): B col n = lane&15, k = (lane>>4)*8 + i.

template<int K, int NC>
__global__ void k_wsplit(const float* __restrict__ W, u32x4* __restrict__ Wf) {
    constexpr int KT = K / 32, NT = NC / 16;
    int tid = blockIdx.x * blockDim.x + threadIdx.x;
    if (tid >= KT * NT * 64) return;
    int lane = tid & 63;
    int ntk  = tid >> 6;           // kt*NT + nt
    int kt = ntk / NT, nt = ntk % NT;
    int kb = kt * 32 + (lane >> 4) * 8;
    int n  = nt * 16 + (lane & 15);
    unsigned int hh[4], ll[4];
    #pragma unroll
    for (int j = 0; j < 4; ++j) {
        float x0 = W[(size_t)(kb + 2 * j) * NC + n];
        float x1 = W[(size_t)(kb + 2 * j + 1) * NC + n];
        split2(x0, x1, hh[j], ll[j]);
    }
    Wf[(size_t)(ntk * 2 + 0) * 64 + lane] = (u32x4){hh[0], hh[1], hh[2], hh[3]};
    Wf[(size_t)(ntk * 2 + 1) * 64 + lane] = (u32x4){ll[0], ll[1], ll[2], ll[3]};
}

// ---- MFMA GEMM: out[M,NC] = A[M,K] @ W[K,NC] (+bias, relu), split-bf16 3-pass ----

template<int K, int NC, bool BIAS, bool RELU, bool BF16OUT>
__global__ __launch_bounds__(128)
void k_gemm_mfma(const float* __restrict__ A, const u32x4* __restrict__ Wf,
                 const float* __restrict__ bias, void* __restrict__ outv, int M) {
    constexpr int KT = K / 32, NT = NC / 16, NTW = NT / 2;
    int lane = threadIdx.x & 63;
    int wid  = threadIdx.x >> 6;
    int lq = lane >> 4;            // 0..3
    int lr = lane & 15;
    int kq = lq * 8;
    int rbase = blockIdx.x * 32;
    int nt0 = wid * NTW;

    f32x4 acc[2][NTW];
    #pragma unroll
    for (int s = 0; s < 2; ++s)
        #pragma unroll
        for (int t = 0; t < NTW; ++t)
            acc[s][t] = (f32x4){0.f, 0.f, 0.f, 0.f};

    for (int kt = 0; kt < KT; ++kt) {
        bf16x8 ah[2], al[2];
        #pragma unroll
        for (int s = 0; s < 2; ++s) {
            int row = rbase + s * 16 + lr;
            const float* Ar = A + (size_t)min(row, M - 1) * K + kt * 32 + kq;
            float4 u = *(const float4*)Ar;
            float4 v = *(const float4*)(Ar + 4);
            unsigned int h0, l0, h1, l1, h2, l2, h3, l3;
            split2(u.x, u.y, h0, l0); split2(u.z, u.w, h1, l1);
            split2(v.x, v.y, h2, l2); split2(v.z, v.w, h3, l3);
            ah[s] = asbf((u32x4){h0, h1, h2, h3});
            al[s] = asbf((u32x4){l0, l1, l2, l3});
        }
        #pragma unroll
        for (int t = 0; t < NTW; ++t) {
            int nt = nt0 + t;
            const u32x4* wp = Wf + (size_t)((kt * NT + nt) * 2) * 64 + lane;
            bf16x8 bh = asbf(wp[0]);
            bf16x8 bl = asbf(wp[64]);
            // D = Ah*Wh + Al*Wh + Ah*Wl  (drop Al*Wl ~ 2^-18)
            acc[0][t] = __builtin_amdgcn_mfma_f32_16x16x32_bf16(ah[0], bh, acc[0][t], 0, 0, 0);
            acc[1][t] = __builtin_amdgcn_mfma_f32_16x16x32_bf16(ah[1], bh, acc[1][t], 0, 0, 0);
            acc[0][t] = __builtin_amdgcn_mfma_f32_16x16x32_bf16(al[0], bh, acc[0][t], 0, 0, 0);
            acc[1][t] = __builtin_amdgcn_mfma_f32_16x16x32_bf16(al[1], bh, acc[1][t], 0, 0, 0);
            acc[0][t] = __builtin_amdgcn_mfma_f32_16x16x32_bf16(ah[0], bl, acc[0][t], 0, 0, 0);
            acc[1][t] = __builtin_amdgcn_mfma_f32_16x16x32_bf16(ah[1], bl, acc[1][t], 0, 0, 0);
        }
    }

    // epilogue: D col = lane&15, row = (lane>>4)*4 + j
    #pragma unroll
    for (int t = 0; t < NTW; ++t) {
        int colg = (nt0 + t) * 16 + lr;
        float bv = BIAS ? bias[colg] : 0.f;
        #pragma unroll
        for (int s = 0; s < 2; ++s) {
            #pragma unroll
            for (int j = 0; j < 4; ++j) {
                int row = rbase + s * 16 + lq * 4 + j;
                if (row < M) {
                    float o = acc[s][t][j] + bv;
                    if (RELU) o = fmaxf(o, 0.f);
                    if (BF16OUT)
                        ((unsigned short*)outv)[(size_t)row * NC + colg] = (unsigned short)bf16rn(o);
                    else
                        ((float*)outv)[(size_t)row * NC + colg] = o;
                }
            }
        }
    }
}

// ---------------- launch ----------------

extern "C" void kernel_launch(void* const* d_in, const int* in_sizes, int n_in,
                              void* d_out, int out_size, void* d_ws, size_t ws_size,
                              hipStream_t stream) {
    const float* x   = (const float*)d_in[0];
    const int*   ei  = (const int*)d_in[1];
    const int*   src = ei;
    const int*   dst = ei + N_EDGES;
    const float* W1  = (const float*)d_in[3];
    const float* b1  = (const float*)d_in[4];
    const float* W2  = (const float*)d_in[5];
    const float* b2  = (const float*)d_in[6];
    float* out = (float*)d_out;

    char* ws = (char*)d_ws;
    size_t o = 0;
    auto carve = [&](size_t bytes) {
        void* p = ws + o;
        o += (bytes + 255) & ~(size_t)255;
        return p;
    };
    int*   cntG   = (int*)  carve((size_t)TOTG * 4);
    int*   curG   = (int*)  carve((size_t)TOTG * 4);
    int*   inclG  = (int*)  carve((size_t)(TOTG + 1) * 4);  // becomes offG in place
    int*   partG  = (int*)  carve(SCAN_BLK * 4);
    int*   len    = (int*)  carve(N_NODES * 4);
    int*   inclN  = (int*)  carve((size_t)(N_NODES + 1) * 4); // becomes offN in place
    int*   partN  = (int*)  carve(SCAN_BLK * 4);
    float* dis    = (float*)carve(N_NODES * 4);
    int*   col    = (int*)  carve((size_t)TOTAL_E * 4);      // compacted CSR (+self)
    float* agg1   = (float*)carve((size_t)N_NODES * 128 * 4);
    float* h1     = (float*)carve((size_t)N_NODES * 256 * 4);
    u32x4* Wf1    = (u32x4*)carve((size_t)(IN_CH/32) * (HID_CH/16) * 2 * 64 * 16);
    u32x4* Wf2    = (u32x4*)carve((size_t)(HID_CH/32) * (OUT_CH/16) * 2 * 64 * 16);
    int*   offG   = inclG;                 // in-place exclusive scan
    int*   offN   = inclN;
    // Aliases (lifetimes by launch order):
    //   xb   aliases h1  : written by k_tobf, dead after agg1; h1 written by gemm1
    //   colG aliases agg1: written by fillG, dead after compact; agg1 written by agg1-pass
    //   t2b  aliases agg1: agg1 dead after gemm1; t2b written by gemm2, read by agg2
    unsigned short* xb  = (unsigned short*)h1;
    int*            colG = (int*)agg1;
    unsigned short* t2b = (unsigned short*)agg1;

    const int B = 256;
    k_tobf  <<<(N_NODES * 128 / 8 + B - 1) / B, B, 0, stream>>>(x, xb, N_NODES * 128 / 8);
    k_initG <<<(TOTG + B - 1) / B, B, 0, stream>>>(cntG, curG);
    k_histG <<<(N_EDGES + B - 1) / B, B, 0, stream>>>(dst, cntG);
    // plane-space scan -> offG
    k_scan1 <<<NBG, SCAN_BLK, 0, stream>>>(cntG, inclG, partG, TOTG);
    k_scan2 <<<1, SCAN_BLK, 0, stream>>>(partG, NBG);
    k_off   <<<(TOTG + 1 + B - 1) / B, B, 0, stream>>>(inclG, cntG, partG, TOTG, N_EDGES);
    // node-space: len/dis, scan -> offN
    k_deg   <<<(N_NODES + B - 1) / B, B, 0, stream>>>(cntG, len, dis);
    k_scan1 <<<NBN, SCAN_BLK, 0, stream>>>(len, inclN, partN, N_NODES);
    k_scan2 <<<1, SCAN_BLK, 0, stream>>>(partN, NBN);
    k_off   <<<(N_NODES + 1 + B - 1) / B, B, 0, stream>>>(inclN, len, partN, N_NODES, TOTAL_E);
    // scatter into planes, then fold into flat CSR
    k_fillG   <<<FILL_BLOCKS, 128, 0, stream>>>(src, dst, offG, curG, colG);
    k_compact <<<N_NODES / 4, 256, 0, stream>>>(offG, colG, offN, col);

    k_wsplit<IN_CH,  HID_CH><<<( (IN_CH/32)*(HID_CH/16)*64 + B - 1) / B, B, 0, stream>>>(W1, Wf1);
    k_wsplit<HID_CH, OUT_CH><<<( (HID_CH/32)*(OUT_CH/16)*64 + B - 1) / B, B, 0, stream>>>(W2, Wf2);

    // layer 1: agg1 = A xb ; h1 = relu(agg1 @ W1 + b1)   (clobbers xb, now dead)
    k_agg_bf<false, false><<<N_NODES / 4, 256, 0, stream>>>(xb, col, offN, len, dis, nullptr, agg1);
    k_gemm_mfma<IN_CH, HID_CH, true, true, false>
        <<<(N_NODES + 31) / 32, 128, 0, stream>>>(agg1, Wf1, b1, h1, N_NODES);

    // layer 2: t2b = bf16(h1 @ W2) ; out = relu(A t2b + b2)
    k_gemm_mfma<HID_CH, OUT_CH, false, false, true>
        <<<(N_NODES + 31) / 32, 128, 0, stream>>>(h1, Wf2, nullptr, t2b, N_NODES);
    k_agg_bf<true, true><<<N_NODES / 4, 256, 0, stream>>>(t2b, col, offN, len, dis, b2, out);
}